// Round 3
// baseline (21.629 us; speedup 1.0000x reference)
//
#include <hip/hip_runtime.h>

#define BB 8
#define SS 64
#define AA 9
#define MM 64
#define NN (SS * SS * AA)  // 36864 boxes per batch image

// Two boxes per thread (i and i+256). Block = 256 threads -> 512 boxes/block.
// No LDS: GT boxes are block-uniform -> scalar (s_load) reads from global.
__global__ __launch_bounds__(256) void frcnn_head_kernel(
    const float* __restrict__ rpn_off,   // (B, N, 4)
    const float* __restrict__ frc_off,   // (B, N, 4)
    const float* __restrict__ gt,        // (B, M, 4)
    const float* __restrict__ anchor_h,  // (A,)
    const float* __restrict__ anchor_w,  // (A,)
    float* __restrict__ out)
{
    const int blocks_per_b = NN / 512;          // 72
    const int b     = blockIdx.x / blocks_per_b;
    const int chunk = blockIdx.x % blocks_per_b;
    const int tid   = threadIdx.x;
    const int i0    = chunk * 512 + tid;
    const int i1    = i0 + 256;

    const float* __restrict__ gt_b = gt + (size_t)b * MM * 4;  // uniform base

    // ---- 1. decode both RPN boxes ----
    const float stride = 800.0f / (float)SS;  // 12.5
    float bx1[2], by1[2], bx2[2], by2[2], areaeps[2];
    const int ii[2] = { i0, i1 };
    #pragma unroll
    for (int k = 0; k < 2; ++k) {
        const int i     = ii[k];
        const int a_idx = i % AA;
        const int xy    = i / AA;
        const int gx    = xy % SS;
        const int gy    = xy / SS;
        const float acx = ((float)gx + 0.5f) * stride;
        const float acy = ((float)gy + 0.5f) * stride;

        const float4 t = ((const float4*)rpn_off)[(size_t)b * NN + i];
        const float aw = anchor_w[a_idx];
        const float ah = anchor_h[a_idx];

        const float pcx = acx + t.x * aw;
        const float pcy = acy + t.y * ah;
        const float pw  = aw * __expf(t.z);
        const float ph  = ah * __expf(t.w);

        bx1[k] = fminf(fmaxf(pcx - 0.5f * pw, 0.0f), 800.0f);
        by1[k] = fminf(fmaxf(pcy - 0.5f * ph, 0.0f), 800.0f);
        bx2[k] = fminf(fmaxf(pcx + 0.5f * pw, 0.0f), 800.0f);
        by2[k] = fminf(fmaxf(pcy + 0.5f * ph, 0.0f), 800.0f);
        areaeps[k] = (bx2[k] - bx1[k]) * (by2[k] - by1[k]) + 1e-9f;
    }

    // ---- 2. division-free max/first-argmax IoU, 4 independent chains ----
    // iou_j > best  <=>  inter_j * bden > bnum * den_j   (dens > 0)
    float bnum[2][4], bden[2][4];
    int   bj[2][4];
    #pragma unroll
    for (int k = 0; k < 2; ++k)
        #pragma unroll
        for (int c = 0; c < 4; ++c) {
            bnum[k][c] = -1.0f; bden[k][c] = 1.0f; bj[k][c] = 16 * c;
        }

    #pragma unroll
    for (int c = 0; c < 4; ++c) {
        #pragma unroll 4
        for (int jc = 0; jc < 16; ++jc) {
            const int j = c * 16 + jc;
            const float gx1 = gt_b[j * 4 + 0], gy1 = gt_b[j * 4 + 1];
            const float gx2 = gt_b[j * 4 + 2], gy2 = gt_b[j * 4 + 3];
            const float ga  = (gx2 - gx1) * (gy2 - gy1);
            #pragma unroll
            for (int k = 0; k < 2; ++k) {
                const float ix1 = fmaxf(bx1[k], gx1);
                const float iy1 = fmaxf(by1[k], gy1);
                const float ix2 = fminf(bx2[k], gx2);
                const float iy2 = fminf(by2[k], gy2);
                const float iw  = fmaxf(ix2 - ix1, 0.0f);
                const float ih  = fmaxf(iy2 - iy1, 0.0f);
                const float inter = iw * ih;
                const float den   = (areaeps[k] + ga) - inter;
                if (inter * bden[k][c] > bnum[k][c] * den) {
                    bnum[k][c] = inter; bden[k][c] = den; bj[k][c] = j;
                }
            }
        }
    }

    // sequential combine (strict > keeps earliest chunk on ties -> first-argmax)
    #pragma unroll
    for (int k = 0; k < 2; ++k)
        #pragma unroll
        for (int c = 1; c < 4; ++c)
            if (bnum[k][c] * bden[k][0] > bnum[k][0] * bden[k][c]) {
                bnum[k][0] = bnum[k][c]; bden[k][0] = bden[k][c]; bj[k][0] = bj[k][c];
            }

    // ---- 3/4. refine + write outputs ----
    const size_t BN = (size_t)BB * NN;
    const size_t o1 = BN * 4;       // is_foreground
    const size_t o2 = o1 + BN;      // best_gt_index
    const size_t o3 = o2 + BN;      // refined_bbox

    #pragma unroll
    for (int k = 0; k < 2; ++k) {
        const int i = ii[k];
        const size_t idx = (size_t)b * NN + i;

        const float4 f = ((const float4*)frc_off)[(size_t)b * NN + i];
        const float w = bx2[k] - bx1[k];
        const float h = by2[k] - by1[k];
        const float rx1 = f.x * w + bx1[k];
        const float ry1 = f.y * h + by1[k];
        const float rx2 = rx1 + __expf(f.z) * w;
        const float ry2 = ry1 + __expf(f.w) * h;

        ((float4*)out)[idx] = make_float4(bx1[k], by1[k], bx2[k], by2[k]);
        out[o1 + idx] = (bnum[k][0] > 0.5f * bden[k][0]) ? 1.0f : 0.0f;
        out[o2 + idx] = (float)bj[k][0];
        ((float4*)(out + o3))[idx] = make_float4(rx1, ry1, rx2, ry2);
    }
}

extern "C" void kernel_launch(void* const* d_in, const int* in_sizes, int n_in,
                              void* d_out, int out_size, void* d_ws, size_t ws_size,
                              hipStream_t stream) {
    const float* rpn_off  = (const float*)d_in[0];
    const float* frc_off  = (const float*)d_in[1];
    const float* gt       = (const float*)d_in[2];
    const float* anchor_h = (const float*)d_in[3];
    const float* anchor_w = (const float*)d_in[4];
    float* out = (float*)d_out;

    const int grid = BB * (NN / 512);  // 576 blocks
    frcnn_head_kernel<<<grid, 256, 0, stream>>>(rpn_off, frc_off, gt,
                                                anchor_h, anchor_w, out);
}

// Round 4
// 20.599 us; speedup vs baseline: 1.0500x; 1.0500x over previous
//
#include <hip/hip_runtime.h>

#define BB 8
#define SS 64
#define AA 9
#define MM 64
#define NN (SS * SS * AA)  // 36864 boxes per batch image

// Two boxes per thread (i and i+256). Block = 256 threads -> 512 boxes/block.
// GT boxes + areas staged in LDS (uniform-address broadcast reads, no conflicts).
__global__ __launch_bounds__(256) void frcnn_head_kernel(
    const float* __restrict__ rpn_off,   // (B, N, 4)
    const float* __restrict__ frc_off,   // (B, N, 4)
    const float* __restrict__ gt,        // (B, M, 4)
    const float* __restrict__ anchor_h,  // (A,)
    const float* __restrict__ anchor_w,  // (A,)
    float* __restrict__ out)
{
    __shared__ float gt_s[MM * 4];
    __shared__ float area_s[MM];
    __shared__ float ah_s[AA];
    __shared__ float aw_s[AA];

    const int blocks_per_b = NN / 512;          // 72
    const int b     = blockIdx.x / blocks_per_b;
    const int chunk = blockIdx.x % blocks_per_b;
    const int tid   = threadIdx.x;
    const int i0    = chunk * 512 + tid;
    const int i1    = i0 + 256;
    const int ii[2] = { i0, i1 };

    // Issue ALL global loads up front so HBM latency hides under the IoU loop.
    const float4 t0 = ((const float4*)rpn_off)[(size_t)b * NN + i0];
    const float4 t1 = ((const float4*)rpn_off)[(size_t)b * NN + i1];
    const float4 f0 = ((const float4*)frc_off)[(size_t)b * NN + i0];
    const float4 f1 = ((const float4*)frc_off)[(size_t)b * NN + i1];
    const float4 tt[2] = { t0, t1 };
    const float4 ff[2] = { f0, f1 };

    if (tid < MM * 4) gt_s[tid] = gt[(size_t)b * MM * 4 + tid];
    if (tid < AA) { ah_s[tid] = anchor_h[tid]; aw_s[tid] = anchor_w[tid]; }
    __syncthreads();
    if (tid < MM) {
        const float gx1 = gt_s[tid * 4 + 0], gy1 = gt_s[tid * 4 + 1];
        const float gx2 = gt_s[tid * 4 + 2], gy2 = gt_s[tid * 4 + 3];
        area_s[tid] = (gx2 - gx1) * (gy2 - gy1);
    }
    __syncthreads();

    // ---- 1. decode both RPN boxes ----
    const float stride = 800.0f / (float)SS;  // 12.5
    float bx1[2], by1[2], bx2[2], by2[2], areaeps[2];
    #pragma unroll
    for (int k = 0; k < 2; ++k) {
        const int i     = ii[k];
        const int a_idx = i % AA;
        const int xy    = i / AA;
        const int gx    = xy % SS;
        const int gy    = xy / SS;
        const float acx = ((float)gx + 0.5f) * stride;
        const float acy = ((float)gy + 0.5f) * stride;

        const float4 t = tt[k];
        const float aw = aw_s[a_idx];
        const float ah = ah_s[a_idx];

        const float pcx = acx + t.x * aw;
        const float pcy = acy + t.y * ah;
        const float pw  = aw * __expf(t.z);
        const float ph  = ah * __expf(t.w);

        bx1[k] = fminf(fmaxf(pcx - 0.5f * pw, 0.0f), 800.0f);
        by1[k] = fminf(fmaxf(pcy - 0.5f * ph, 0.0f), 800.0f);
        bx2[k] = fminf(fmaxf(pcx + 0.5f * pw, 0.0f), 800.0f);
        by2[k] = fminf(fmaxf(pcy + 0.5f * ph, 0.0f), 800.0f);
        areaeps[k] = (bx2[k] - bx1[k]) * (by2[k] - by1[k]) + 1e-9f;
    }

    // ---- 2. division-free max/first-argmax IoU, 4 independent chains ----
    float bnum[2][4], bden[2][4];
    int   bj[2][4];
    #pragma unroll
    for (int k = 0; k < 2; ++k)
        #pragma unroll
        for (int c = 0; c < 4; ++c) {
            bnum[k][c] = -1.0f; bden[k][c] = 1.0f; bj[k][c] = 16 * c;
        }

    #pragma unroll
    for (int c = 0; c < 4; ++c) {
        #pragma unroll 4
        for (int jc = 0; jc < 16; ++jc) {
            const int j = c * 16 + jc;
            const float gx1 = gt_s[j * 4 + 0], gy1 = gt_s[j * 4 + 1];
            const float gx2 = gt_s[j * 4 + 2], gy2 = gt_s[j * 4 + 3];
            const float ga  = area_s[j];
            #pragma unroll
            for (int k = 0; k < 2; ++k) {
                const float ix1 = fmaxf(bx1[k], gx1);
                const float iy1 = fmaxf(by1[k], gy1);
                const float ix2 = fminf(bx2[k], gx2);
                const float iy2 = fminf(by2[k], gy2);
                const float iw  = fmaxf(ix2 - ix1, 0.0f);
                const float ih  = fmaxf(iy2 - iy1, 0.0f);
                const float inter = iw * ih;
                const float den   = (areaeps[k] + ga) - inter;
                if (inter * bden[k][c] > bnum[k][c] * den) {
                    bnum[k][c] = inter; bden[k][c] = den; bj[k][c] = j;
                }
            }
        }
    }

    #pragma unroll
    for (int k = 0; k < 2; ++k)
        #pragma unroll
        for (int c = 1; c < 4; ++c)
            if (bnum[k][c] * bden[k][0] > bnum[k][0] * bden[k][c]) {
                bnum[k][0] = bnum[k][c]; bden[k][0] = bden[k][c]; bj[k][0] = bj[k][c];
            }

    // ---- 3/4. refine + write outputs ----
    const size_t BN = (size_t)BB * NN;
    const size_t o1 = BN * 4;       // is_foreground
    const size_t o2 = o1 + BN;      // best_gt_index
    const size_t o3 = o2 + BN;      // refined_bbox

    #pragma unroll
    for (int k = 0; k < 2; ++k) {
        const int i = ii[k];
        const size_t idx = (size_t)b * NN + i;

        const float4 f = ff[k];
        const float w = bx2[k] - bx1[k];
        const float h = by2[k] - by1[k];
        const float rx1 = f.x * w + bx1[k];
        const float ry1 = f.y * h + by1[k];
        const float rx2 = rx1 + __expf(f.z) * w;
        const float ry2 = ry1 + __expf(f.w) * h;

        ((float4*)out)[idx] = make_float4(bx1[k], by1[k], bx2[k], by2[k]);
        out[o1 + idx] = (bnum[k][0] > 0.5f * bden[k][0]) ? 1.0f : 0.0f;
        out[o2 + idx] = (float)bj[k][0];
        ((float4*)(out + o3))[idx] = make_float4(rx1, ry1, rx2, ry2);
    }
}

extern "C" void kernel_launch(void* const* d_in, const int* in_sizes, int n_in,
                              void* d_out, int out_size, void* d_ws, size_t ws_size,
                              hipStream_t stream) {
    const float* rpn_off  = (const float*)d_in[0];
    const float* frc_off  = (const float*)d_in[1];
    const float* gt       = (const float*)d_in[2];
    const float* anchor_h = (const float*)d_in[3];
    const float* anchor_w = (const float*)d_in[4];
    float* out = (float*)d_out;

    const int grid = BB * (NN / 512);  // 576 blocks
    frcnn_head_kernel<<<grid, 256, 0, stream>>>(rpn_off, frc_off, gt,
                                                anchor_h, anchor_w, out);
}

// Round 5
// 20.298 us; speedup vs baseline: 1.0655x; 1.0148x over previous
//
#include <hip/hip_runtime.h>

#define BB 8
#define SS 64
#define AA 9
#define MM 64
#define NN (SS * SS * AA)  // 36864 boxes per batch image

// 64-thread blocks (1 wave), 2 boxes per thread -> 128 boxes/block.
// NN/128 = 288 blocks per batch, 8*288 = 2304 blocks = exactly 9 per CU
// (perfect load balance; same 2.25 waves/SIMD as the 256-thread config).
__global__ __launch_bounds__(64) void frcnn_head_kernel(
    const float* __restrict__ rpn_off,   // (B, N, 4)
    const float* __restrict__ frc_off,   // (B, N, 4)
    const float* __restrict__ gt,        // (B, M, 4)
    const float* __restrict__ anchor_h,  // (A,)
    const float* __restrict__ anchor_w,  // (A,)
    float* __restrict__ out)
{
    __shared__ float4 gt_s4[MM];
    __shared__ float  area_s[MM];
    __shared__ float  ah_s[AA];
    __shared__ float  aw_s[AA];

    const int blocks_per_b = NN / 128;          // 288
    const int b     = blockIdx.x / blocks_per_b;
    const int chunk = blockIdx.x % blocks_per_b;
    const int tid   = threadIdx.x;              // 0..63
    const int i0    = chunk * 128 + tid;
    const int i1    = i0 + 64;
    const int ii[2] = { i0, i1 };

    // Issue all per-box global loads up front: latency hides under staging+loop.
    const float4 t0 = ((const float4*)rpn_off)[(size_t)b * NN + i0];
    const float4 t1 = ((const float4*)rpn_off)[(size_t)b * NN + i1];
    const float4 f0 = ((const float4*)frc_off)[(size_t)b * NN + i0];
    const float4 f1 = ((const float4*)frc_off)[(size_t)b * NN + i1];
    const float4 tt[2] = { t0, t1 };
    const float4 ff[2] = { f0, f1 };

    // Stage GT: one float4 + one area per lane, single barrier.
    {
        const float4 g = ((const float4*)gt)[(size_t)b * MM + tid];
        gt_s4[tid]  = g;
        area_s[tid] = (g.z - g.x) * (g.w - g.y);
        if (tid < AA) { ah_s[tid] = anchor_h[tid]; aw_s[tid] = anchor_w[tid]; }
    }
    __syncthreads();

    // ---- 1. decode both RPN boxes ----
    const float stride = 800.0f / (float)SS;  // 12.5
    float bx1[2], by1[2], bx2[2], by2[2], areaeps[2];
    #pragma unroll
    for (int k = 0; k < 2; ++k) {
        const int i     = ii[k];
        const int a_idx = i % AA;
        const int xy    = i / AA;
        const int gx    = xy % SS;
        const int gy    = xy / SS;
        const float acx = ((float)gx + 0.5f) * stride;
        const float acy = ((float)gy + 0.5f) * stride;

        const float4 t = tt[k];
        const float aw = aw_s[a_idx];
        const float ah = ah_s[a_idx];

        const float pcx = acx + t.x * aw;
        const float pcy = acy + t.y * ah;
        const float pw  = aw * __expf(t.z);
        const float ph  = ah * __expf(t.w);

        bx1[k] = fminf(fmaxf(pcx - 0.5f * pw, 0.0f), 800.0f);
        by1[k] = fminf(fmaxf(pcy - 0.5f * ph, 0.0f), 800.0f);
        bx2[k] = fminf(fmaxf(pcx + 0.5f * pw, 0.0f), 800.0f);
        by2[k] = fminf(fmaxf(pcy + 0.5f * ph, 0.0f), 800.0f);
        areaeps[k] = (bx2[k] - bx1[k]) * (by2[k] - by1[k]) + 1e-9f;
    }

    // ---- 2. division-free max/first-argmax IoU, 4 independent chains ----
    // iou_j > best  <=>  inter_j * bden > bnum * den_j   (dens > 0)
    float bnum[2][4], bden[2][4];
    int   bj[2][4];
    #pragma unroll
    for (int k = 0; k < 2; ++k)
        #pragma unroll
        for (int c = 0; c < 4; ++c) {
            bnum[k][c] = -1.0f; bden[k][c] = 1.0f; bj[k][c] = 16 * c;
        }

    #pragma unroll
    for (int c = 0; c < 4; ++c) {
        #pragma unroll 4
        for (int jc = 0; jc < 16; ++jc) {
            const int j = c * 16 + jc;
            const float4 g = gt_s4[j];
            const float ga = area_s[j];
            #pragma unroll
            for (int k = 0; k < 2; ++k) {
                const float ix1 = fmaxf(bx1[k], g.x);
                const float iy1 = fmaxf(by1[k], g.y);
                const float ix2 = fminf(bx2[k], g.z);
                const float iy2 = fminf(by2[k], g.w);
                const float iw  = fmaxf(ix2 - ix1, 0.0f);
                const float ih  = fmaxf(iy2 - iy1, 0.0f);
                const float inter = iw * ih;
                const float den   = (areaeps[k] + ga) - inter;
                if (inter * bden[k][c] > bnum[k][c] * den) {
                    bnum[k][c] = inter; bden[k][c] = den; bj[k][c] = j;
                }
            }
        }
    }

    // sequential combine (strict > keeps earliest chunk on ties -> first-argmax)
    #pragma unroll
    for (int k = 0; k < 2; ++k)
        #pragma unroll
        for (int c = 1; c < 4; ++c)
            if (bnum[k][c] * bden[k][0] > bnum[k][0] * bden[k][c]) {
                bnum[k][0] = bnum[k][c]; bden[k][0] = bden[k][c]; bj[k][0] = bj[k][c];
            }

    // ---- 3/4. refine + write outputs ----
    const size_t BN = (size_t)BB * NN;
    const size_t o1 = BN * 4;       // is_foreground
    const size_t o2 = o1 + BN;      // best_gt_index
    const size_t o3 = o2 + BN;      // refined_bbox

    #pragma unroll
    for (int k = 0; k < 2; ++k) {
        const int i = ii[k];
        const size_t idx = (size_t)b * NN + i;

        const float4 f = ff[k];
        const float w = bx2[k] - bx1[k];
        const float h = by2[k] - by1[k];
        const float rx1 = f.x * w + bx1[k];
        const float ry1 = f.y * h + by1[k];
        const float rx2 = rx1 + __expf(f.z) * w;
        const float ry2 = ry1 + __expf(f.w) * h;

        ((float4*)out)[idx] = make_float4(bx1[k], by1[k], bx2[k], by2[k]);
        out[o1 + idx] = (bnum[k][0] > 0.5f * bden[k][0]) ? 1.0f : 0.0f;
        out[o2 + idx] = (float)bj[k][0];
        ((float4*)(out + o3))[idx] = make_float4(rx1, ry1, rx2, ry2);
    }
}

extern "C" void kernel_launch(void* const* d_in, const int* in_sizes, int n_in,
                              void* d_out, int out_size, void* d_ws, size_t ws_size,
                              hipStream_t stream) {
    const float* rpn_off  = (const float*)d_in[0];
    const float* frc_off  = (const float*)d_in[1];
    const float* gt       = (const float*)d_in[2];
    const float* anchor_h = (const float*)d_in[3];
    const float* anchor_w = (const float*)d_in[4];
    float* out = (float*)d_out;

    const int grid = BB * (NN / 128);  // 2304 blocks = 9 per CU exactly
    frcnn_head_kernel<<<grid, 64, 0, stream>>>(rpn_off, frc_off, gt,
                                               anchor_h, anchor_w, out);
}